// Round 1
// baseline (395.438 us; speedup 1.0000x reference)
//
#include <hip/hip_runtime.h>

#define BIG_Z_F 1000000.0f
#define N_MESH 8

// Native Clang vector types — required by __builtin_nontemporal_* (HIP's
// float4/int4 are structs and are rejected by the builtin).
typedef float f4 __attribute__((ext_vector_type(4)));
typedef int   i4 __attribute__((ext_vector_type(4)));

// R10: single fused kernel.
//  - Old kernel A (cross-mesh reduction) folded into the per-mesh interp
//    kernel: each (n,q) thread re-reads the 8 zbuf rows with PLAIN (cached)
//    loads — zbuf is 8 MB, L2/L3-resident, 8x reuse across blockIdx.y — and
//    recomputes dup/argmin locally. Removes: kernel A dispatch (1 wave/SIMD,
//    latency-bound), the win4 ws round-trip, and one inter-kernel drain.
//  - vert_vis folded in: valid pixels scatter vv[pfaces[3p+k]]=1 directly
//    (branched, ~1/8 lanes active). Removes: faceflag ws round-trip + the
//    tail dispatch + another drain. vv is zeroed by a tiny leading kernel.
//  - Reduction uses running scalars (cnt/best/bi) + uniform-select of the
//    own-row f4; NO z[8][4] array indexed by runtime n (scratch-spill trap).
//  - R9 lessons kept: branchless gather/interp path, 16B NT loads for
//    stream-once inputs, 16B NT stores for all outputs, c4-chunked interp
//    loop with 16-f4 live set. R8's half-row batching regressed (VGPRs) —
//    do not re-batch.

// ---------------------------------------------------------------------------
// Tiny init kernel: zero vertex-visibility accumulator (40 KB).
// ---------------------------------------------------------------------------
__global__ __launch_bounds__(256) void zero_vv(
    float* __restrict__ vv, int V)
{
    const int i = blockIdx.x * blockDim.x + threadIdx.x;
    if (i < V) vv[i] = 0.0f;
}

// ---------------------------------------------------------------------------
// Fused kernel: per-(mesh, 4 pixels). Cross-mesh reduction + mask/zb +
// p/d/bc outputs + gather-interp out_map + direct vv scatter.
// ---------------------------------------------------------------------------
__global__ __launch_bounds__(256) void raster_fused(
    const f4* __restrict__ zbuf4,   // (N, HW/4) — cached loads, 8x reuse
    const i4* __restrict__ p2f4,    // (N, HW/4)
    const f4* __restrict__ bary4,   // (N, HW/4, 3)
    const f4* __restrict__ dists4,  // (N, HW/4)
    const float* __restrict__ fmem, // (F,3,C)
    const int* __restrict__ pfaces, // (F,3)
    const int* __restrict__ mdp,    // scalar mask_duplicate
    f4* __restrict__ out_map4,      // (N,C,HW/4)
    f4* __restrict__ maskO4,        // (N, HW/4)
    f4* __restrict__ zbO4,          // (N, HW/4)
    f4* __restrict__ pO4,           // (N, HW/4)
    f4* __restrict__ dO4,           // (N, HW/4)
    f4* __restrict__ bcO4,          // (N, HW/4, 3)
    float* __restrict__ vv,         // (V), pre-zeroed by zero_vv
    int HW4, int C)
{
    const int q = blockIdx.x * blockDim.x + threadIdx.x;
    if (q >= HW4) return;
    const int n    = blockIdx.y;
    const int idx4 = n * HW4 + q;
    const int md   = *mdp;

    // ---- cross-mesh reduction (running scalars; no runtime-indexed array)
    int   cnt[4]  = { 0, 0, 0, 0 };
    float best[4] = { __builtin_inff(), __builtin_inff(),
                      __builtin_inff(), __builtin_inff() };
    int   bi[4]   = { 0, 0, 0, 0 };
    f4 zown;
    #pragma unroll
    for (int nn = 0; nn < N_MESH; ++nn) {
        const f4 v = zbuf4[nn * HW4 + q];     // plain load: L2/L3-resident
        if (nn == n) zown = v;                // uniform select (n is uniform)
        #pragma unroll
        for (int j = 0; j < 4; ++j) {
            const float zv = v[j];
            cnt[j] += (zv > -1.0f) ? 1 : 0;
            const float t = (zv < 0.0f) ? BIG_Z_F : zv;
            if (t < best[j]) { best[j] = t; bi[j] = nn; } // strict < => first-win tie
        }
    }

    bool dup[4];
    {
        f4 m, zb;
        #pragma unroll
        for (int j = 0; j < 4; ++j) {
            const bool dup0 = (cnt[j] > 1);
            dup[j] = dup0 && ((md != 0) || (n != bi[j]));
            m[j]  = (zown[j] >= 0.0f) ? 1.0f : 0.0f;
            zb[j] = dup[j] ? -1.0f : zown[j];
        }
        __builtin_nontemporal_store(m,  &maskO4[idx4]);
        __builtin_nontemporal_store(zb, &zbO4[idx4]);
    }

    // ---- per-entry p/d/bc outputs (identical semantics to R9 kernel B)
    const i4 praw = __builtin_nontemporal_load(&p2f4[idx4]);
    const f4 drw  = __builtin_nontemporal_load(&dists4[idx4]);
    const f4 bv0  = __builtin_nontemporal_load(&bary4[idx4 * 3 + 0]); // p0.xyz p1.x
    const f4 bv1  = __builtin_nontemporal_load(&bary4[idx4 * 3 + 1]); // p1.yz  p2.xy
    const f4 bv2  = __builtin_nontemporal_load(&bary4[idx4 * 3 + 2]); // p2.z   p3.xyz
    const int   pr[4] = { praw.x, praw.y, praw.z, praw.w };
    const float dr[4] = { drw.x, drw.y, drw.z, drw.w };
    const float br[4][3] = {
        { bv0.x, bv0.y, bv0.z },
        { bv0.w, bv1.x, bv1.y },
        { bv1.z, bv1.w, bv2.x },
        { bv2.y, bv2.z, bv2.w },
    };

    float bst[4][3];   // values stored to bcO (dup -> -1)
    float bc[4][3];    // compute coefficients (invalid -> 0 => out = 0)
    int   safe[4];
    bool  vld[4];
    f4 pOv, dOv;
    #pragma unroll
    for (int j = 0; j < 4; ++j) {
        const int  p     = dup[j] ? -1 : pr[j];
        const bool valid = (p >= 0);
        #pragma unroll
        for (int k = 0; k < 3; ++k) {
            bst[j][k] = dup[j] ? -1.0f : br[j][k];
            bc[j][k]  = valid ? bst[j][k] : 0.0f;
        }
        safe[j] = valid ? p : 0;
        vld[j]  = valid;
        pOv[j]  = (float)p;
        dOv[j]  = dup[j] ? -1.0f : dr[j];
    }
    __builtin_nontemporal_store(pOv, &pO4[idx4]);
    __builtin_nontemporal_store(dOv, &dO4[idx4]);
    {
        f4 c0, c1, c2;
        c0.x = bst[0][0]; c0.y = bst[0][1]; c0.z = bst[0][2]; c0.w = bst[1][0];
        c1.x = bst[1][1]; c1.y = bst[1][2]; c1.z = bst[2][0]; c1.w = bst[2][1];
        c2.x = bst[2][2]; c2.y = bst[3][0]; c2.z = bst[3][1]; c2.w = bst[3][2];
        __builtin_nontemporal_store(c0, &bcO4[idx4 * 3 + 0]);
        __builtin_nontemporal_store(c1, &bcO4[idx4 * 3 + 1]);
        __builtin_nontemporal_store(c2, &bcO4[idx4 * 3 + 2]);
    }

    // ---- direct vertex-visibility scatter (replaces faceflag + vert_vis).
    // ~1/8 lanes active; 4B stores into a 40 KB L2-resident region.
    #pragma unroll
    for (int j = 0; j < 4; ++j) {
        if (vld[j]) {
            const int b = safe[j] * 3;
            vv[pfaces[b + 0]] = 1.0f;
            vv[pfaces[b + 1]] = 1.0f;
            vv[pfaces[b + 2]] = 1.0f;
        }
    }

    // ---- gather + interp (unchanged R7/R9 structure: branchless, c4 chunks)
    const float* ab[4];
    #pragma unroll
    for (int j = 0; j < 4; ++j)
        ab[j] = fmem + (size_t)safe[j] * 3 * C;

    #pragma unroll
    for (int c4 = 0; c4 < 32; c4 += 4) {     // C == 32
        f4 r[4];   // r[j] = channels c4..c4+3 of pixel j (channel-major)
        #pragma unroll
        for (int j = 0; j < 4; ++j) {
            const float* a = ab[j];
            const f4 a0 = *(const f4*)(a + c4);
            const f4 a1 = *(const f4*)(a + C + c4);
            const f4 a2 = *(const f4*)(a + 2 * C + c4);
            r[j] = bc[j][0] * a0 + bc[j][1] * a1 + bc[j][2] * a2;
        }
        #pragma unroll
        for (int k = 0; k < 4; ++k) {        // transpose to pixel-major
            f4 o;
            o.x = r[0][k]; o.y = r[1][k]; o.z = r[2][k]; o.w = r[3][k];
            __builtin_nontemporal_store(o, &out_map4[(size_t)(n * C + c4 + k) * HW4 + q]);
        }
    }
}

extern "C" void kernel_launch(void* const* d_in, const int* in_sizes, int n_in,
                              void* d_out, int out_size, void* d_ws, size_t ws_size,
                              hipStream_t stream) {
    const float* zbuf   = (const float*)d_in[0];
    const int*   p2f    = (const int*)  d_in[1];
    const float* bary   = (const float*)d_in[2];
    const float* dists  = (const float*)d_in[3];
    const float* fmem   = (const float*)d_in[4];
    const int*   pfaces = (const int*)  d_in[5];
    // d_in[6] = num_verts (device scalar; V derived from out_size instead)
    const int*   mdp    = (const int*)  d_in[7];

    const long long P  = in_sizes[0];        // N*H*W*K = 2097152
    const int HW  = (int)(P / N_MESH);       // 262144 pixels
    const int HW4 = HW / 4;                  // 65536
    const int F3  = in_sizes[5];             // F*3
    const int C   = in_sizes[4] / F3;        // 32
    const int V   = (int)((long long)out_size - P * C - 7 * P);  // 10002

    float* out     = (float*)d_out;
    float* out_map = out;                    // P*C
    float* vv      = out_map + P * C;        // V
    float* maskO   = vv + V;                 // P
    float* zbO     = maskO + P;              // P
    float* pO      = zbO + P;                // P
    float* dO      = pO + P;                 // P
    float* bcO     = dO + P;                 // 3P

    zero_vv<<<dim3((V + 255) / 256), dim3(256), 0, stream>>>(vv, V);

    raster_fused<<<dim3(HW4 / 256, N_MESH), dim3(256), 0, stream>>>(
        (const f4*)zbuf, (const i4*)p2f, (const f4*)bary, (const f4*)dists,
        fmem, pfaces, mdp,
        (f4*)out_map, (f4*)maskO, (f4*)zbO, (f4*)pO, (f4*)dO, (f4*)bcO,
        vv, HW4, C);
}